// Round 4
// baseline (591.778 us; speedup 1.0000x reference)
//
#include <hip/hip_runtime.h>

#define DEV __device__ __forceinline__

typedef unsigned int uint;
typedef unsigned short ushort;
typedef __attribute__((ext_vector_type(8))) short short8;
typedef __attribute__((ext_vector_type(4))) float f32x4;

DEV ushort f2bf(float x){ uint u = __float_as_uint(x); return (ushort)((u + 0x7fffu + ((u >> 16) & 1u)) >> 16); }
DEV float bf2f(ushort u){ return __uint_as_float(((uint)u) << 16); }
DEV float bflo(uint p){ return __uint_as_float(p << 16); }
DEV float bfhi(uint p){ return __uint_as_float(p & 0xffff0000u); }

DEV void gl_lds16(const void* g, void* l){
  __builtin_amdgcn_global_load_lds((const __attribute__((address_space(1))) void*)g,
                                   (__attribute__((address_space(3))) void*)l, 16, 0, 0);
}

DEV void mfma16x16x32(f32x4& d, short8 a, short8 b){
  asm volatile("v_mfma_f32_16x16x32_bf16 %0, %1, %2, %0" : "+v"(d) : "v"(a), "v"(b));
}

// ---------------- weight transpose + fp32->bf16 cast: W[K][N] -> Wt[N][2048] ----------------
__global__ __launch_bounds__(256) void transpose_cast(const float* __restrict__ W,
                                                      ushort* __restrict__ Wt, int N){
  __shared__ ushort tile[64][66];
  const int kt = blockIdx.x << 6, nt = blockIdx.y << 6;
  const int t = threadIdx.x;
#pragma unroll
  for (int j = 0; j < 16; ++j){
    int idx = t + (j << 8);
    int r = idx >> 6, c = idx & 63;
    tile[r][c] = f2bf(W[(size_t)(kt + r) * N + nt + c]);
  }
  __syncthreads();
#pragma unroll
  for (int j = 0; j < 8; ++j){
    int idx = t + (j << 8);
    int n = idx >> 5, kp = (idx & 31) << 1;
    uint v = (uint)tile[kp][n] | ((uint)tile[kp + 1][n] << 16);
    *(uint*)&Wt[(size_t)(nt + n) * 2048 + kt + kp] = v;
  }
}

// ---------------- embedding gather + cast ----------------
__global__ __launch_bounds__(256) void gather_cast(const int* __restrict__ X,
                                                   const float* __restrict__ emb,
                                                   ushort* __restrict__ Xb){
  const int row = blockIdx.x;
  const int t = threadIdx.x;
  const int tok = X[row];
  const float4* src = (const float4*)(emb + (size_t)tok * 2048) + t * 2;
  float4 a = src[0], b = src[1];
  uint4 o;
  o.x = (uint)f2bf(a.x) | ((uint)f2bf(a.y) << 16);
  o.y = (uint)f2bf(a.z) | ((uint)f2bf(a.w) << 16);
  o.z = (uint)f2bf(b.x) | ((uint)f2bf(b.y) << 16);
  o.w = (uint)f2bf(b.z) | ((uint)f2bf(b.w) << 16);
  *(uint4*)(Xb + (size_t)row * 2048 + t * 8) = o;
}

// ---------------- GEMM: C[M][N] = A[M][K] * Bt[N][K]^T ----------------
// MODE 0: QKV fused (N=3072): n<2048 -> Q[m][n]; 2048..2559 -> K scatter; 2560..3071 -> V scatter
// MODE 1: out fp32 = acc + bias[n]
template<int MODE>
__global__ __launch_bounds__(256) void gemm_bt(const ushort* __restrict__ A,
                                               const ushort* __restrict__ Bt, int K,
                                               ushort* __restrict__ oq, ushort* __restrict__ ok,
                                               ushort* __restrict__ ov, float* __restrict__ of,
                                               const float* __restrict__ bias, int N){
  __shared__ __align__(16) ushort As[128 * 64];
  __shared__ __align__(16) ushort Bs[128 * 64];
  const int t = threadIdx.x;
  const int bm = blockIdx.x << 7, bn = blockIdx.y << 7;
  const int wid = t >> 6, lane = t & 63;
  const int wm = (wid >> 1) << 6, wn = (wid & 1) << 6;
  const int lr = lane & 15;
  const int lkb = (lane >> 4) << 3;
  f32x4 acc[4][4] = {};
  const int kIters = K >> 6;
  for (int kt = 0; kt < kIters; ++kt){
    const int k0 = kt << 6;
#pragma unroll
    for (int j = 0; j < 4; ++j){
      int idx = t + (j << 8);
      int r = idx >> 3, c = (idx & 7) << 3;
      gl_lds16(A + (size_t)(bm + r) * K + k0 + c, (char*)As + (size_t)idx * 16);
      gl_lds16(Bt + (size_t)(bn + r) * K + k0 + c, (char*)Bs + (size_t)idx * 16);
    }
    __syncthreads();
#pragma unroll
    for (int ks = 0; ks < 2; ++ks){
      short8 a[4], b[4];
#pragma unroll
      for (int i = 0; i < 4; ++i){
        a[i] = *(const short8*)&As[(wm + i * 16 + lr) * 64 + ks * 32 + lkb];
        b[i] = *(const short8*)&Bs[(wn + i * 16 + lr) * 64 + ks * 32 + lkb];
      }
#pragma unroll
      for (int i = 0; i < 4; ++i)
#pragma unroll
        for (int jn = 0; jn < 4; ++jn)
          mfma16x16x32(acc[i][jn], a[i], b[jn]);
    }
    __syncthreads();
  }
  const int rbase = (lane >> 4) << 2;
#pragma unroll
  for (int i = 0; i < 4; ++i){
#pragma unroll
    for (int jn = 0; jn < 4; ++jn){
#pragma unroll
      for (int r = 0; r < 4; ++r){
        int m = bm + wm + i * 16 + rbase + r;
        int n = bn + wn + jn * 16 + lr;
        float v = acc[i][jn][r];
        if (MODE == 0){
          if (n < 2048){
            oq[(size_t)m * 2048 + n] = f2bf(v);
          } else {
            int nl = n - 2048;
            ushort* dst = (nl >> 9) ? ov : ok;
            int nl2 = nl & 511;
            int kh = nl2 >> 6, dk = nl2 & 63;
            int bb = m >> 11, s = m & 2047;
            dst[(((size_t)bb * 8 + kh) * 2048 + s) * 64 + dk] = f2bf(v);
          }
        } else {
          of[(size_t)m * N + n] = v + bias[n];
        }
      }
    }
  }
}

// ---------------- sliding-window attention ----------------
// block = (b, kh, 64-query tile); 4 waves = 4 g-heads. Window = 65 keys [qg-64, qg].
__global__ __launch_bounds__(256) void swattn(const ushort* __restrict__ Qb,
                                              const ushort* __restrict__ Kb,
                                              const ushort* __restrict__ Vb,
                                              ushort* __restrict__ Ctx){
  __shared__ ushort Ks[128][66];
  __shared__ ushort Vs[128][66];
  __shared__ float pl[4][64];
  const int bid = blockIdx.x;
  const int qt = bid & 31, kh = (bid >> 5) & 7, b = bid >> 8;
  const int q0 = qt << 6;
  const int t = threadIdx.x, wid = t >> 6, lane = t & 63;
  const ushort* Kg = Kb + ((size_t)b * 8 + kh) * 2048 * 64;
  const ushort* Vg = Vb + ((size_t)b * 8 + kh) * 2048 * 64;
#pragma unroll
  for (int j = 0; j < 16; ++j){
    int idx = t + (j << 8);
    int r = idx >> 5, c = (idx & 31) << 1;
    int pos = q0 - 64 + r;
    uint kv = 0, vv = 0;
    if (pos >= 0){
      kv = *(const uint*)(Kg + (size_t)pos * 64 + c);
      vv = *(const uint*)(Vg + (size_t)pos * 64 + c);
    }
    *(uint*)&Ks[r][c] = kv;
    *(uint*)&Vs[r][c] = vv;
  }
  __syncthreads();
  const int qh = kh * 4 + wid;
  const ushort* Qbase = Qb + ((size_t)b * 2048 + q0) * 2048 + qh * 64;
  ushort* Cbase = Ctx + ((size_t)b * 2048 + q0) * 2048 + qh * 64;
  const float scale = 0.125f;
  for (int q = 0; q < 64; ++q){
    const int qg = q0 + q;
    const uint* qp = (const uint*)(Qbase + (size_t)q * 2048);
    float s = 0.f;
#pragma unroll 8
    for (int d2 = 0; d2 < 32; ++d2){
      uint qv = qp[d2];
      uint kv = *(const uint*)&Ks[q + lane][d2 << 1];
      s = fmaf(bflo(kv), bflo(qv), s);
      s = fmaf(bfhi(kv), bfhi(qv), s);
    }
    // self key (w = 64): 64-lane dot + butterfly reduce
    float part = bf2f(((const ushort*)qp)[lane]) * bf2f(Ks[q + 64][lane]);
#pragma unroll
    for (int off = 32; off >= 1; off >>= 1) part += __shfl_xor(part, off);
    float sself = part * scale;
    s *= scale;
    float sc = (lane >= 64 - qg) ? s : -1e30f;
    float mx = sc;
#pragma unroll
    for (int off = 32; off >= 1; off >>= 1) mx = fmaxf(mx, __shfl_xor(mx, off));
    mx = fmaxf(mx, sself);
    float p = __expf(sc - mx);
    float ps = __expf(sself - mx);
    float den = p;
#pragma unroll
    for (int off = 32; off >= 1; off >>= 1) den += __shfl_xor(den, off);
    den += ps;
    float inv = 1.0f / den;
    pl[wid][lane] = p * inv;
    float pself = ps * inv;
    float accv = pself * bf2f(Vs[q + 64][lane]);
#pragma unroll 8
    for (int w2 = 0; w2 < 64; ++w2){
      accv = fmaf(pl[wid][w2], bf2f(Vs[q + w2][lane]), accv);
    }
    Cbase[(size_t)q * 2048 + lane] = f2bf(accv);
  }
}

extern "C" void kernel_launch(void* const* d_in, const int* in_sizes, int n_in,
                              void* d_out, int out_size, void* d_ws, size_t ws_size,
                              hipStream_t stream){
  (void)in_sizes; (void)n_in; (void)out_size; (void)ws_size;
  const int*   X   = (const int*)d_in[0];
  const float* emb = (const float*)d_in[1];
  const float* Wk  = (const float*)d_in[2];
  const float* Wv  = (const float*)d_in[3];
  const float* Wq  = (const float*)d_in[4];
  const float* Wo  = (const float*)d_in[5];
  const float* bo  = (const float*)d_in[6];
  float* out = (float*)d_out;

  ushort* ws    = (ushort*)d_ws;
  ushort* WqkvT = ws;                                  // [3072][2048]
  ushort* WoT   = WqkvT + (size_t)3072 * 2048;         // [2048][2048]
  ushort* Xb    = WoT   + (size_t)2048 * 2048;         // [4096][2048]
  ushort* Qb    = Xb    + (size_t)4096 * 2048;         // [4096][2048]
  ushort* Kb    = Qb    + (size_t)4096 * 2048;         // [2][8][2048][64]
  ushort* Vb    = Kb    + (size_t)2 * 8 * 2048 * 64;
  ushort* Ctx   = Vb    + (size_t)2 * 8 * 2048 * 64;   // [4096][2048]

  transpose_cast<<<dim3(32, 32), 256, 0, stream>>>(Wq, WqkvT, 2048);
  transpose_cast<<<dim3(32, 8),  256, 0, stream>>>(Wk, WqkvT + (size_t)2048 * 2048, 512);
  transpose_cast<<<dim3(32, 8),  256, 0, stream>>>(Wv, WqkvT + (size_t)2560 * 2048, 512);
  transpose_cast<<<dim3(32, 32), 256, 0, stream>>>(Wo, WoT, 2048);
  gather_cast<<<4096, 256, 0, stream>>>(X, emb, Xb);
  gemm_bt<0><<<dim3(32, 24), 256, 0, stream>>>(Xb, WqkvT, 2048, Qb, Kb, Vb, nullptr, nullptr, 3072);
  swattn<<<512, 256, 0, stream>>>(Qb, Kb, Vb, Ctx);
  gemm_bt<1><<<dim3(32, 16), 256, 0, stream>>>(Ctx, WoT, 2048, nullptr, nullptr, nullptr, out, bo, 2048);
}

// Round 10
// 472.384 us; speedup vs baseline: 1.2527x; 1.2527x over previous
//
#include <hip/hip_runtime.h>

#define DEV __device__ __forceinline__

typedef unsigned int uint;
typedef unsigned short ushort;
typedef __attribute__((ext_vector_type(8))) short short8;
typedef __attribute__((ext_vector_type(4))) float f32x4;

DEV ushort f2bf(float x){ uint u = __float_as_uint(x); return (ushort)((u + 0x7fffu + ((u >> 16) & 1u)) >> 16); }
DEV float bf2f(ushort u){ return __uint_as_float(((uint)u) << 16); }

DEV void gl_lds16(const void* g, void* l){
  __builtin_amdgcn_global_load_lds((const __attribute__((address_space(1))) void*)g,
                                   (__attribute__((address_space(3))) void*)l, 16, 0, 0);
}

DEV void mfma16x16x32(f32x4& d, short8 a, short8 b){
  asm volatile("v_mfma_f32_16x16x32_bf16 %0, %1, %2, %0" : "+v"(d) : "v"(a), "v"(b));
}

// MFMA(asm) -> VALU hazard fence: the hazard recognizer can't see into inline asm,
// so guarantee wait-states before VALU reads of accumulators.
DEV void mfma_fence(){
  __builtin_amdgcn_sched_barrier(0);
  asm volatile("s_nop 7\n\ts_nop 7" :::);
  __builtin_amdgcn_sched_barrier(0);
}

// ---------------- weight transpose + fp32->bf16 cast: W[K][N] -> Wt[N][2048] ----------------
__global__ __launch_bounds__(256) void transpose_cast(const float* __restrict__ W,
                                                      ushort* __restrict__ Wt, int N){
  __shared__ ushort tile[64][66];
  const int kt = blockIdx.x << 6, nt = blockIdx.y << 6;
  const int t = threadIdx.x;
#pragma unroll
  for (int j = 0; j < 16; ++j){
    int idx = t + (j << 8);
    int r = idx >> 6, c = idx & 63;
    tile[r][c] = f2bf(W[(size_t)(kt + r) * N + nt + c]);
  }
  __syncthreads();
#pragma unroll
  for (int j = 0; j < 8; ++j){
    int idx = t + (j << 8);
    int n = idx >> 5, kp = (idx & 31) << 1;
    uint v = (uint)tile[kp][n] | ((uint)tile[kp + 1][n] << 16);
    *(uint*)&Wt[(size_t)(nt + n) * 2048 + kt + kp] = v;
  }
}

// ---------------- embedding gather + cast ----------------
__global__ __launch_bounds__(256) void gather_cast(const int* __restrict__ X,
                                                   const float* __restrict__ emb,
                                                   ushort* __restrict__ Xb){
  const int row = blockIdx.x;
  const int t = threadIdx.x;
  const int tok = X[row];
  const float4* src = (const float4*)(emb + (size_t)tok * 2048) + t * 2;
  float4 a = src[0], b = src[1];
  uint4 o;
  o.x = (uint)f2bf(a.x) | ((uint)f2bf(a.y) << 16);
  o.y = (uint)f2bf(a.z) | ((uint)f2bf(a.w) << 16);
  o.z = (uint)f2bf(b.x) | ((uint)f2bf(b.y) << 16);
  o.w = (uint)f2bf(b.z) | ((uint)f2bf(b.w) << 16);
  *(uint4*)(Xb + (size_t)row * 2048 + t * 8) = o;
}

// ---------------- GEMM: C[M][N] = A[M][K] * Bt[N][K]^T ----------------
// MODE 0: QKV fused (N=3072): n<2048 -> Q[m][n]; 2048..2559 -> K scatter [b][kh][s][dk];
//         2560..3071 -> V scatter TRANSPOSED [b][kh][dk][s]
// MODE 1: out fp32 = acc + bias[n]
template<int MODE>
__global__ __launch_bounds__(256) void gemm_bt(const ushort* __restrict__ A,
                                               const ushort* __restrict__ Bt, int K,
                                               ushort* __restrict__ oq, ushort* __restrict__ ok,
                                               ushort* __restrict__ ov, float* __restrict__ of,
                                               const float* __restrict__ bias, int N){
  __shared__ __align__(16) ushort As[128 * 64];
  __shared__ __align__(16) ushort Bs[128 * 64];
  const int t = threadIdx.x;
  const int bm = blockIdx.x << 7, bn = blockIdx.y << 7;
  const int wid = t >> 6, lane = t & 63;
  const int wm = (wid >> 1) << 6, wn = (wid & 1) << 6;
  const int lr = lane & 15;
  const int lkb = (lane >> 4) << 3;
  f32x4 acc[4][4] = {};
  const int kIters = K >> 6;
  for (int kt = 0; kt < kIters; ++kt){
    const int k0 = kt << 6;
#pragma unroll
    for (int j = 0; j < 4; ++j){
      int idx = t + (j << 8);
      int r = idx >> 3, c = (idx & 7) << 3;
      gl_lds16(A + (size_t)(bm + r) * K + k0 + c, (char*)As + (size_t)idx * 16);
      gl_lds16(Bt + (size_t)(bn + r) * K + k0 + c, (char*)Bs + (size_t)idx * 16);
    }
    __syncthreads();
#pragma unroll
    for (int ks = 0; ks < 2; ++ks){
      short8 a[4], b[4];
#pragma unroll
      for (int i = 0; i < 4; ++i){
        a[i] = *(const short8*)&As[(wm + i * 16 + lr) * 64 + ks * 32 + lkb];
        b[i] = *(const short8*)&Bs[(wn + i * 16 + lr) * 64 + ks * 32 + lkb];
      }
#pragma unroll
      for (int i = 0; i < 4; ++i)
#pragma unroll
        for (int jn = 0; jn < 4; ++jn)
          mfma16x16x32(acc[i][jn], a[i], b[jn]);
    }
    __syncthreads();
  }
  mfma_fence();
  const int rbase = (lane >> 4) << 2;
#pragma unroll
  for (int i = 0; i < 4; ++i){
#pragma unroll
    for (int jn = 0; jn < 4; ++jn){
#pragma unroll
      for (int r = 0; r < 4; ++r){
        int m = bm + wm + i * 16 + rbase + r;
        int n = bn + wn + jn * 16 + lr;
        float v = acc[i][jn][r];
        if (MODE == 0){
          if (n < 2048){
            oq[(size_t)m * 2048 + n] = f2bf(v);
          } else {
            int nl = n - 2048;
            int nl2 = nl & 511;
            int kh = nl2 >> 6, dk = nl2 & 63;
            int bb = m >> 11, s = m & 2047;
            if (nl >> 9)
              ov[(((size_t)bb * 8 + kh) * 64 + dk) * 2048 + s] = f2bf(v);   // V transposed
            else
              ok[(((size_t)bb * 8 + kh) * 2048 + s) * 64 + dk] = f2bf(v);
          }
        } else {
          of[(size_t)m * N + n] = v + bias[n];
        }
      }
    }
  }
}

// ---------------- sliding-window attention, MFMA ----------------
// block = (b, kh, 32-query tile); 4 waves = 4 g-heads share K/V window in LDS.
// Window keys: pos = q0-64+j, j in [0,96). Valid for query qv=q-q0: j in [max(qv,64-q0), qv+64].
__global__ __launch_bounds__(256) void swattn_mfma(const ushort* __restrict__ Qb,
                                                   const ushort* __restrict__ Kb,
                                                   const ushort* __restrict__ Vtg,
                                                   ushort* __restrict__ Ctx){
  __shared__ __align__(16) ushort Ks[96][72];       // [j][d], pad 8
  __shared__ __align__(16) ushort Vt[64][104];      // [d][j], pad 8
  __shared__ __align__(16) ushort Ps[4][32][104];   // per-wave P (unnormalized), [q][j], pad 8
  const int bid = blockIdx.x;
  const int qt = bid & 63, kh = (bid >> 6) & 7, b = bid >> 9;
  const int q0 = qt << 5;
  const int t = threadIdx.x, wid = t >> 6, lane = t & 63;
  const int pos0 = q0 - 64;
  const int jc = lane & 15;            // col-in-tile / row-in-tile index
  const int kq8 = (lane >> 4) << 3;    // k-offset of this lane's input fragment
  const int qg4 = (lane >> 4) << 2;    // acc row base

  // stage K tile: Ks[j][d]
  const ushort* Kg = Kb + ((size_t)b * 8 + kh) * 2048 * 64;
#pragma unroll
  for (int it = 0; it < 3; ++it){
    int idx = t + (it << 8);           // 768 x uint4 = 96 rows x 8 chunks
    int j = idx >> 3, c = (idx & 7) << 3;
    int pos = pos0 + j;
    uint4 val = make_uint4(0, 0, 0, 0);
    if (pos >= 0) val = *(const uint4*)(Kg + (size_t)pos * 64 + c);
    *(uint4*)&Ks[j][c] = val;
  }
  // stage V tile transposed: Vt[d][j] from Vtg rows (contiguous in s)
  const ushort* Vg = Vtg + ((size_t)b * 8 + kh) * 64 * 2048;
#pragma unroll
  for (int it = 0; it < 3; ++it){
    int idx = t + (it << 8);           // 768 x uint4 = 64 rows x 12 chunks
    int d = idx / 12, c = idx - d * 12;
    int j = c << 3;
    int pos = pos0 + j;
    uint4 val = make_uint4(0, 0, 0, 0);
    if (pos >= 0) val = *(const uint4*)(Vg + (size_t)d * 2048 + pos);
    *(uint4*)&Vt[d][j] = val;
  }
  // Q fragments straight to registers
  const int qh = kh * 4 + wid;
  const ushort* Qrow = Qb + ((size_t)(b * 2048 + q0)) * 2048 + (size_t)qh * 64;
  short8 qa[2][2];
#pragma unroll
  for (int mt = 0; mt < 2; ++mt)
#pragma unroll
    for (int ks = 0; ks < 2; ++ks)
      qa[mt][ks] = *(const short8*)(Qrow + (size_t)(mt * 16 + jc) * 2048 + ks * 32 + kq8);
  __syncthreads();

  // QK^T: S[32q][96j]
  f32x4 s[2][6] = {};
#pragma unroll
  for (int nt = 0; nt < 6; ++nt){
    short8 kb0 = *(const short8*)&Ks[nt * 16 + jc][kq8];
    short8 kb1 = *(const short8*)&Ks[nt * 16 + jc][32 + kq8];
#pragma unroll
    for (int mt = 0; mt < 2; ++mt){
      mfma16x16x32(s[mt][nt], qa[mt][0], kb0);
      mfma16x16x32(s[mt][nt], qa[mt][1], kb1);
    }
  }
  mfma_fence();   // MFMA(asm) results read by VALU below

  // masked softmax, wave-parallel (16-lane groups own rows).
  // Store UNNORMALIZED exp(s - mx) in bf16; divide after PV in fp32.
  const float scale = 0.125f;
  float invden[2][4];
#pragma unroll
  for (int mt = 0; mt < 2; ++mt){
#pragma unroll
    for (int r = 0; r < 4; ++r){
      int qv = mt * 16 + qg4 + r;                 // 0..31
      int lo = max(qv, 64 - q0);
      int hi = qv + 64;
      float vals[6];
      float mx = -1e30f;
#pragma unroll
      for (int nt = 0; nt < 6; ++nt){
        int j = nt * 16 + jc;
        float x = s[mt][nt][r] * scale;
        vals[nt] = (j >= lo && j <= hi) ? x : -1e30f;
        mx = fmaxf(mx, vals[nt]);
      }
#pragma unroll
      for (int off = 1; off <= 8; off <<= 1) mx = fmaxf(mx, __shfl_xor(mx, off));
      float sum = 0.f;
#pragma unroll
      for (int nt = 0; nt < 6; ++nt){
        float p = __expf(vals[nt] - mx);
        vals[nt] = p;
        sum += p;
      }
#pragma unroll
      for (int off = 1; off <= 8; off <<= 1) sum += __shfl_xor(sum, off);
      invden[mt][r] = 1.0f / sum;
#pragma unroll
      for (int nt = 0; nt < 6; ++nt)
        Ps[wid][qv][nt * 16 + jc] = f2bf(vals[nt]);
    }
  }
  __syncthreads();

  // PV: ctx[32q][64d] = P[32][96] * V[96][64] (B-frags from Vt rows)
  f32x4 o[2][4] = {};
#pragma unroll
  for (int ks = 0; ks < 3; ++ks){
    short8 pa0 = *(const short8*)&Ps[wid][jc][ks * 32 + kq8];
    short8 pa1 = *(const short8*)&Ps[wid][16 + jc][ks * 32 + kq8];
#pragma unroll
    for (int nt = 0; nt < 4; ++nt){
      short8 vb = *(const short8*)&Vt[nt * 16 + jc][ks * 32 + kq8];
      mfma16x16x32(o[0][nt], pa0, vb);
      mfma16x16x32(o[1][nt], pa1, vb);
    }
  }
  mfma_fence();   // MFMA(asm) results read by VALU below

  // write ctx, renormalize in fp32
  ushort* Cb = Ctx + ((size_t)(b * 2048 + q0)) * 2048 + (size_t)qh * 64;
#pragma unroll
  for (int mt = 0; mt < 2; ++mt)
#pragma unroll
    for (int nt = 0; nt < 4; ++nt)
#pragma unroll
      for (int r = 0; r < 4; ++r)
        Cb[(size_t)(mt * 16 + qg4 + r) * 2048 + nt * 16 + jc] = f2bf(o[mt][nt][r] * invden[mt][r]);
}

extern "C" void kernel_launch(void* const* d_in, const int* in_sizes, int n_in,
                              void* d_out, int out_size, void* d_ws, size_t ws_size,
                              hipStream_t stream){
  (void)in_sizes; (void)n_in; (void)out_size; (void)ws_size;
  const int*   X   = (const int*)d_in[0];
  const float* emb = (const float*)d_in[1];
  const float* Wk  = (const float*)d_in[2];
  const float* Wv  = (const float*)d_in[3];
  const float* Wq  = (const float*)d_in[4];
  const float* Wo  = (const float*)d_in[5];
  const float* bo  = (const float*)d_in[6];
  float* out = (float*)d_out;

  ushort* ws    = (ushort*)d_ws;
  ushort* WqkvT = ws;                                  // [3072][2048]
  ushort* WoT   = WqkvT + (size_t)3072 * 2048;         // [2048][2048]
  ushort* Xb    = WoT   + (size_t)2048 * 2048;         // [4096][2048]
  ushort* Qb    = Xb    + (size_t)4096 * 2048;         // [4096][2048]
  ushort* Kb    = Qb    + (size_t)4096 * 2048;         // [2][8][2048][64]
  ushort* Vb    = Kb    + (size_t)2 * 8 * 2048 * 64;   // [2][8][64][2048] (transposed)
  ushort* Ctx   = Vb    + (size_t)2 * 8 * 2048 * 64;   // [4096][2048]

  transpose_cast<<<dim3(32, 32), 256, 0, stream>>>(Wq, WqkvT, 2048);
  transpose_cast<<<dim3(32, 8),  256, 0, stream>>>(Wk, WqkvT + (size_t)2048 * 2048, 512);
  transpose_cast<<<dim3(32, 8),  256, 0, stream>>>(Wv, WqkvT + (size_t)2560 * 2048, 512);
  transpose_cast<<<dim3(32, 32), 256, 0, stream>>>(Wo, WoT, 2048);
  gather_cast<<<4096, 256, 0, stream>>>(X, emb, Xb);
  gemm_bt<0><<<dim3(32, 24), 256, 0, stream>>>(Xb, WqkvT, 2048, Qb, Kb, Vb, nullptr, nullptr, 3072);
  swattn_mfma<<<1024, 256, 0, stream>>>(Qb, Kb, Vb, Ctx);
  gemm_bt<1><<<dim3(32, 16), 256, 0, stream>>>(Ctx, WoT, 2048, nullptr, nullptr, nullptr, out, bo, 2048);
}